// Round 2
// baseline (163.119 us; speedup 1.0000x reference)
//
#include <hip/hip_runtime.h>
#include <stdint.h>

#define NPTS 4096
#define NW   64            // 64-bit words per adjacency row
#define SENT NPTS
#define MAXSP 512

// ---------------- lock-free min union-find (deterministic fixed point) ------
__device__ __forceinline__ int uf_find(int* p, int x){
  while (true){
    int px = p[x];
    if (px == x) return x;
    int ppx = p[px];
    if (ppx == px) return px;
    p[x] = ppx;            // path halving (benign race; links only decrease)
    x = ppx;
  }
}

// read-only find: used when no one is writing parent concurrently
__device__ __forceinline__ int uf_find_ro(const int* __restrict__ p, int x){
  int px;
  while ((px = p[x]) != x) x = px;
  return x;
}

// CAS-return-driven hook loop: progress guaranteed by atomic return values
// (max(a,b) strictly decreases on every failed CAS), never relies on a
// plain re-read being fresh (per-XCD L1/L2 are not coherent for plain loads).
__device__ __forceinline__ void uf_union(int* p, int a, int b){
  a = uf_find(p, a);
  b = uf_find(p, b);
  while (a != b){
    int lo = min(a, b), hi = max(a, b);
    int old = atomicCAS(&p[hi], hi, lo);
    if (old == hi || old == lo) return;  // hooked (or already hooked to lo)
    a = lo; b = old;                     // old = true parent of hi (< hi)
  }
}

// ---------------- K1: adjacency bitset + degree/core + parent init ----------
// one 64-lane wave per row i; word k built with __ballot over lanes (j = k*64+lane)
__global__ void k_adj(const float* __restrict__ coords,
                      unsigned long long* __restrict__ adj,
                      int* __restrict__ core, int* __restrict__ parent){
#pragma clang fp contract(off)
  int wid  = (blockIdx.x * blockDim.x + threadIdx.x) >> 6;   // global row id
  int lane = threadIdx.x & 63;
  int b = wid >> 12;
  int i = wid & (NPTS - 1);
  const float* cb = coords + (size_t)b * NPTS * 3;
  float xi = cb[i*3+0], yi = cb[i*3+1], zi = cb[i*3+2];
  // sq: round each square, then sequential adds (XLA mul + reduce, no FMA)
  float sqi = ((xi*xi) + (yi*yi)) + (zi*zi);
  const float EPS2 = (float)(0.06 * 0.06);   // f64 product -> f32 (JAX weak-type)
  unsigned long long myword = 0ULL;
  int deg = 0;
  #pragma unroll 4
  for (int k = 0; k < 64; ++k){
    int j = (k << 6) + lane;
    float xj = cb[j*3+0], yj = cb[j*3+1], zj = cb[j*3+2];
    float sqj = ((xj*xj) + (yj*yj)) + (zj*zj);
    // dot: ascending-k FMA chain from zero acc (Eigen/XLA gebp): first
    // product plainly rounded, then fused madds
    float dot = __builtin_fmaf(zi, zj, __builtin_fmaf(yi, yj, xi * xj));
    float d2  = (sqi + sqj) - (2.0f * dot);   // *2 exact; sub individually rounded
    unsigned long long bal = __ballot(d2 <= EPS2);
    if (lane == k) myword = bal;
    deg += __popcll(bal);
  }
  adj[(size_t)wid * NW + lane] = myword;
  if (lane == 0){
    core[wid]   = (deg >= 3) ? 1 : 0;   // MIN_SAMPLES=3, count includes self
    parent[wid] = i;
  }
}

// ---------------- K2: core bitset (one wave per batch) ----------------------
__global__ void k_corebits(const int* __restrict__ core,
                           unsigned long long* __restrict__ corebits){
  int b = blockIdx.x;
  int lane = threadIdx.x;   // 64 threads
  unsigned long long myword = 0ULL;
  for (int k = 0; k < 64; ++k){
    unsigned long long bal = __ballot(core[(b << 12) + (k << 6) + lane] != 0);
    if (lane == k) myword = bal;
  }
  corebits[(b << 6) + lane] = myword;
}

// ---------------- K3: union core-core edges (j > i) -------------------------
__global__ void k_union(const unsigned long long* __restrict__ adj,
                        const unsigned long long* __restrict__ corebits,
                        const int* __restrict__ core, int* __restrict__ parent){
  int gid = blockIdx.x * blockDim.x + threadIdx.x;  // (b, i, word)
  int w = gid & 63;
  int i = (gid >> 6) & (NPTS - 1);
  int b = gid >> 18;
  if (!core[(b << 12) + i]) return;
  unsigned long long m = adj[(size_t)gid] & corebits[(b << 6) + w];
  int base = w << 6;
  int lo = i - base;
  if (lo >= 63) return;                     // whole word has j <= i
  if (lo >= 0) m &= (~0ULL) << (lo + 1);    // keep j > i
  int* p = parent + (b << 12);
  while (m){
    int bit = __builtin_ctzll(m);
    m &= m - 1;
    uf_union(p, i, base + bit);
  }
}

// ---------------- K4: labels (core: root; border: min core-neighbor root) ---
// parent is CONSTANT during this kernel (read-only finds) -> no staleness.
__global__ void k_labels(const unsigned long long* __restrict__ adj,
                         const unsigned long long* __restrict__ corebits,
                         const int* __restrict__ core,
                         const int* __restrict__ parent,
                         int* __restrict__ labels){
  int wid  = (blockIdx.x * blockDim.x + threadIdx.x) >> 6;
  int lane = threadIdx.x & 63;
  int b = wid >> 12;
  int i = wid & (NPTS - 1);
  const int* p = parent + (b << 12);
  unsigned long long m = adj[(size_t)wid * NW + lane] & corebits[(b << 6) + lane];
  int mn = SENT;
  int base = lane << 6;
  while (m){
    int bit = __builtin_ctzll(m);
    m &= m - 1;
    mn = min(mn, uf_find_ro(p, base + bit));
  }
  #pragma unroll
  for (int off = 32; off; off >>= 1) mn = min(mn, __shfl_xor(mn, off));
  if (lane == 0){
    labels[wid] = core[wid] ? uf_find_ro(p, i) : mn;   // SENT if no core nbr
  }
}

// ---------------- K5: per-batch finalize (noise fill, compact, cap) ---------
__global__ __launch_bounds__(1024) void k_final(const int* __restrict__ labels_g,
                                                int* __restrict__ out){
  __shared__ int LAB[NPTS];
  __shared__ int A[NPTS];
  __shared__ int B[NPTS];
  __shared__ int scanbuf[1024];
  __shared__ int sMost;
  int b = blockIdx.x;
  int t = threadIdx.x;
  const int* lg = labels_g + (b << 12);

  for (int s = 0; s < 4; ++s){ int v = (t << 2) + s; LAB[v] = lg[v]; A[v] = 0; }
  if (t == 0) sMost = -1;
  __syncthreads();
  // counts over non-noise labels
  for (int s = 0; s < 4; ++s){ int l = LAB[(t << 2) + s]; if (l < SENT) atomicAdd(&A[l], 1); }
  __syncthreads();
  // most common: max count, tie -> smallest label (argmax first-index)
  for (int s = 0; s < 4; ++s){
    int v = (t << 2) + s; int c = A[v];
    if (c > 0) atomicMax(&sMost, (c << 13) | (4095 - v));
  }
  __syncthreads();
  int most = (sMost >= 0) ? (4095 - (sMost & 8191)) : 0;
  // fill noise, reset B for presence
  for (int s = 0; s < 4; ++s){ int v = (t << 2) + s; if (LAB[v] == SENT) LAB[v] = most; B[v] = 0; }
  __syncthreads();
  for (int s = 0; s < 4; ++s) B[LAB[(t << 2) + s]] = 1;
  __syncthreads();
  // inclusive scan of presence -> rank = cumsum-1 (in place in B)
  int pv[4]; int ls = 0;
  for (int s = 0; s < 4; ++s){ pv[s] = B[(t << 2) + s]; ls += pv[s]; }
  scanbuf[t] = ls;
  __syncthreads();
  for (int off = 1; off < 1024; off <<= 1){
    int x = scanbuf[t];
    int y = (t >= off) ? scanbuf[t - off] : 0;
    __syncthreads();
    scanbuf[t] = x + y;
    __syncthreads();
  }
  int ncl = scanbuf[1023];
  int run = (t > 0) ? scanbuf[t - 1] : 0;
  for (int s = 0; s < 4; ++s){ run += pv[s]; B[(t << 2) + s] = run - 1; }
  __syncthreads();
  for (int s = 0; s < 4; ++s){ int v = (t << 2) + s; LAB[v] = B[LAB[v]]; }
  __syncthreads();
  if (ncl > MAXSP){
    // counts2 of compacted labels
    for (int s = 0; s < 4; ++s) A[(t << 2) + s] = 0;
    __syncthreads();
    for (int s = 0; s < 4; ++s) atomicAdd(&A[LAB[(t << 2) + s]], 1);
    __syncthreads();
    // stable ascending argsort rank via key = count*NPTS + v; last 512 get arange
    for (int s = 0; s < 4; ++s){
      int v = (t << 2) + s;
      int keyv = A[v] * NPTS + v;
      int pos = 0;
      for (int u = 0; u < NPTS; ++u) pos += ((A[u] * NPTS + u) < keyv) ? 1 : 0;
      B[v] = (pos >= NPTS - MAXSP) ? (pos - (NPTS - MAXSP)) : 0;
    }
    __syncthreads();
    for (int s = 0; s < 4; ++s){ int v = (t << 2) + s; LAB[v] = B[LAB[v]]; }
    __syncthreads();
  }
  int* og = out + (b << 12);
  for (int s = 0; s < 4; ++s){ int v = (t << 2) + s; og[v] = LAB[v]; }
}

// ---------------- launch ----------------------------------------------------
extern "C" void kernel_launch(void* const* d_in, const int* in_sizes, int n_in,
                              void* d_out, int out_size, void* d_ws, size_t ws_size,
                              hipStream_t stream){
  const float* coords = (const float*)d_in[0];
  int* out = (int*)d_out;
  int batches = in_sizes[0] / (NPTS * 3);   // 8

  char* ws = (char*)d_ws;
  unsigned long long* adj = (unsigned long long*)ws;                  // B*4096*64*8 = 16 MB
  size_t off = (size_t)batches * NPTS * NW * sizeof(unsigned long long);
  int* parent = (int*)(ws + off); off += (size_t)batches * NPTS * sizeof(int);
  int* core   = (int*)(ws + off); off += (size_t)batches * NPTS * sizeof(int);
  unsigned long long* corebits = (unsigned long long*)(ws + off);
  off += (size_t)batches * 64 * sizeof(unsigned long long);
  int* labels = (int*)(ws + off); off += (size_t)batches * NPTS * sizeof(int);

  // K1: one wave per row (4 waves / 256-thread block)
  k_adj<<<batches * (NPTS / 4), 256, 0, stream>>>(coords, adj, core, parent);
  // K2: core bitset
  k_corebits<<<batches, 64, 0, stream>>>(core, corebits);
  // K3: union core-core edges
  k_union<<<(batches * NPTS * NW) / 256, 256, 0, stream>>>(adj, corebits, core, parent);
  // K4: label extraction (one wave per row)
  k_labels<<<batches * (NPTS / 4), 256, 0, stream>>>(adj, corebits, core, parent, labels);
  // K5: per-batch finalize
  k_final<<<batches, 1024, 0, stream>>>(labels, out);
}

// Round 3
// 145.355 us; speedup vs baseline: 1.1222x; 1.1222x over previous
//
#include <hip/hip_runtime.h>
#include <stdint.h>

#define NPTS 4096
#define NW   64            // 64-bit words per adjacency row
#define SENT NPTS
#define MAXSP 512
#define ROWS 8             // rows per wave in k_adj

// ---------------- lock-free min union-find (deterministic fixed point) ------
__device__ __forceinline__ int uf_find(int* p, int x){
  while (true){
    int px = p[x];
    if (px == x) return x;
    int ppx = p[px];
    if (ppx == px) return px;
    p[x] = ppx;            // path halving (benign race; links only decrease)
    x = ppx;
  }
}

__device__ __forceinline__ int uf_find_ro(const int* __restrict__ p, int x){
  int px;
  while ((px = p[x]) != x) x = px;
  return x;
}

// CAS-return-driven hook loop: progress guaranteed by atomic return values
// (max(a,b) strictly decreases on every failed CAS).
__device__ __forceinline__ void uf_union(int* p, int a, int b){
  a = uf_find(p, a);
  b = uf_find(p, b);
  while (a != b){
    int lo = min(a, b), hi = max(a, b);
    int old = atomicCAS(&p[hi], hi, lo);
    if (old == hi || old == lo) return;
    a = lo; b = old;
  }
}

// ---------------- K0: pack coords into float4(x,y,z,sq) ---------------------
__global__ void k_prep(const float* __restrict__ coords,
                       float4* __restrict__ pts){
#pragma clang fp contract(off)
  int g = blockIdx.x * blockDim.x + threadIdx.x;   // 8*4096
  float x = coords[g*3+0], y = coords[g*3+1], z = coords[g*3+2];
  // sq: round each square, then sequential adds (XLA mul + reduce, no FMA)
  float sq = ((x*x) + (y*y)) + (z*z);
  pts[g] = make_float4(x, y, z, sq);
}

// ---------------- K1: adjacency bitset + degree/core ------------------------
// one wave handles ROWS=8 rows; word k built with __ballot (j = k*64+lane)
__global__ void k_adj(const float4* __restrict__ pts,
                      unsigned long long* __restrict__ adj,
                      int* __restrict__ core){
#pragma clang fp contract(off)
  int wv   = (blockIdx.x * blockDim.x + threadIdx.x) >> 6;   // 4096 waves
  int lane = threadIdx.x & 63;
  int b  = wv >> 9;                 // 512 waves per batch
  int i0 = (wv & 511) << 3;         // first of 8 rows
  const float4* pb = pts + (b << 12);
  float4 pi[ROWS];
  #pragma unroll
  for (int r = 0; r < ROWS; ++r) pi[r] = pb[i0 + r];
  const float EPS2 = (float)(0.06 * 0.06);
  unsigned long long w[ROWS];
  int deg[ROWS];
  #pragma unroll
  for (int r = 0; r < ROWS; ++r){ w[r] = 0ULL; deg[r] = 0; }
  #pragma unroll 2
  for (int k = 0; k < 64; ++k){
    float4 pj = pb[(k << 6) + lane];
    #pragma unroll
    for (int r = 0; r < ROWS; ++r){
      // dot: ascending-k FMA chain, first product plainly rounded (XLA gebp)
      float dot = __builtin_fmaf(pi[r].z, pj.z,
                  __builtin_fmaf(pi[r].y, pj.y, pi[r].x * pj.x));
      // rn(s - rn(2*dot)) == fma(-2,dot,s) since 2*dot is exact
      float d2 = __builtin_fmaf(-2.0f, dot, pi[r].w + pj.w);
      unsigned long long bal = __ballot(d2 <= EPS2);
      if (lane == k) w[r] = bal;
      deg[r] += __popcll(bal);
    }
  }
  size_t rowg = ((size_t)b << 12) + i0;
  #pragma unroll
  for (int r = 0; r < ROWS; ++r) adj[(rowg + r) * NW + lane] = w[r];
  if (lane == 0){
    #pragma unroll
    for (int r = 0; r < ROWS; ++r) core[rowg + r] = (deg[r] >= 3) ? 1 : 0;
  }
}

// ---------------- K2: core bitset (one wave per batch) ----------------------
__global__ void k_corebits(const int* __restrict__ core,
                           unsigned long long* __restrict__ corebits){
  int b = blockIdx.x;
  int lane = threadIdx.x;   // 64 threads
  unsigned long long myword = 0ULL;
  for (int k = 0; k < 64; ++k){
    unsigned long long bal = __ballot(core[(b << 12) + (k << 6) + lane] != 0);
    if (lane == k) myword = bal;
  }
  corebits[(b << 6) + lane] = myword;
}

// ---------------- K3a: min-neighbor hook (no atomics) -----------------------
// parent[i] = min core neighbor (incl. self) — plain store to own slot.
__global__ void k_hook(const unsigned long long* __restrict__ adj,
                       const unsigned long long* __restrict__ corebits,
                       const int* __restrict__ core,
                       int* __restrict__ parent){
  int wv   = (blockIdx.x * blockDim.x + threadIdx.x) >> 6;   // global row
  int lane = threadIdx.x & 63;
  int b = wv >> 12;
  if (!core[wv]) return;
  unsigned long long m = adj[(size_t)wv * NW + lane] & corebits[(b << 6) + lane];
  int mn = SENT;
  if (m) mn = (lane << 6) + __builtin_ctzll(m);
  #pragma unroll
  for (int off = 32; off; off >>= 1) mn = min(mn, __shfl_xor(mn, off));
  if (lane == 0) parent[wv] = mn;   // mn <= i (self bit is set)
}

// ---------------- K3b: union remaining inter-tree edges (j > i) -------------
__global__ void k_union2(const unsigned long long* __restrict__ adj,
                         const unsigned long long* __restrict__ corebits,
                         const int* __restrict__ core,
                         int* __restrict__ parent){
  int wv   = (blockIdx.x * blockDim.x + threadIdx.x) >> 6;
  int lane = threadIdx.x & 63;
  int b = wv >> 12;
  int i = wv & (NPTS - 1);
  if (!core[wv]) return;
  unsigned long long m = adj[(size_t)wv * NW + lane] & corebits[(b << 6) + lane];
  int base = lane << 6;
  if (base + 63 <= i) m = 0ULL;                       // whole word j <= i
  else if (base <= i) m &= (~0ULL) << (i - base + 1); // keep j > i
  int* p = parent + (b << 12);
  while (m){
    int bit = __builtin_ctzll(m);
    m &= m - 1;
    uf_union(p, i, base + bit);
  }
}

// ---------------- K4: labels (core: root; border: min core-neighbor root) ---
// parent is CONSTANT during this kernel (read-only finds).
__global__ void k_labels(const unsigned long long* __restrict__ adj,
                         const unsigned long long* __restrict__ corebits,
                         const int* __restrict__ core,
                         const int* __restrict__ parent,
                         int* __restrict__ labels){
  int wv   = (blockIdx.x * blockDim.x + threadIdx.x) >> 6;
  int lane = threadIdx.x & 63;
  int b = wv >> 12;
  int i = wv & (NPTS - 1);
  const int* p = parent + (b << 12);
  unsigned long long m = adj[(size_t)wv * NW + lane] & corebits[(b << 6) + lane];
  int mn = SENT;
  int base = lane << 6;
  while (m){
    int bit = __builtin_ctzll(m);
    m &= m - 1;
    mn = min(mn, uf_find_ro(p, base + bit));
  }
  #pragma unroll
  for (int off = 32; off; off >>= 1) mn = min(mn, __shfl_xor(mn, off));
  if (lane == 0){
    labels[wv] = core[wv] ? uf_find_ro(p, i) : mn;   // SENT if no core nbr
  }
}

// ---------------- K5: per-batch finalize (noise fill, compact, cap) ---------
__global__ __launch_bounds__(1024) void k_final(const int* __restrict__ labels_g,
                                                int* __restrict__ out){
  __shared__ int LAB[NPTS];
  __shared__ int A[NPTS];
  __shared__ int B[NPTS];
  __shared__ int scanbuf[1024];
  __shared__ int sMost;
  int b = blockIdx.x;
  int t = threadIdx.x;
  const int* lg = labels_g + (b << 12);

  for (int s = 0; s < 4; ++s){ int v = (t << 2) + s; LAB[v] = lg[v]; A[v] = 0; }
  if (t == 0) sMost = -1;
  __syncthreads();
  for (int s = 0; s < 4; ++s){ int l = LAB[(t << 2) + s]; if (l < SENT) atomicAdd(&A[l], 1); }
  __syncthreads();
  for (int s = 0; s < 4; ++s){
    int v = (t << 2) + s; int c = A[v];
    if (c > 0) atomicMax(&sMost, (c << 13) | (4095 - v));
  }
  __syncthreads();
  int most = (sMost >= 0) ? (4095 - (sMost & 8191)) : 0;
  for (int s = 0; s < 4; ++s){ int v = (t << 2) + s; if (LAB[v] == SENT) LAB[v] = most; B[v] = 0; }
  __syncthreads();
  for (int s = 0; s < 4; ++s) B[LAB[(t << 2) + s]] = 1;
  __syncthreads();
  int pv[4]; int ls = 0;
  for (int s = 0; s < 4; ++s){ pv[s] = B[(t << 2) + s]; ls += pv[s]; }
  scanbuf[t] = ls;
  __syncthreads();
  for (int off = 1; off < 1024; off <<= 1){
    int x = scanbuf[t];
    int y = (t >= off) ? scanbuf[t - off] : 0;
    __syncthreads();
    scanbuf[t] = x + y;
    __syncthreads();
  }
  int ncl = scanbuf[1023];
  int run = (t > 0) ? scanbuf[t - 1] : 0;
  for (int s = 0; s < 4; ++s){ run += pv[s]; B[(t << 2) + s] = run - 1; }
  __syncthreads();
  for (int s = 0; s < 4; ++s){ int v = (t << 2) + s; LAB[v] = B[LAB[v]]; }
  __syncthreads();
  if (ncl > MAXSP){
    for (int s = 0; s < 4; ++s) A[(t << 2) + s] = 0;
    __syncthreads();
    for (int s = 0; s < 4; ++s) atomicAdd(&A[LAB[(t << 2) + s]], 1);
    __syncthreads();
    for (int s = 0; s < 4; ++s){
      int v = (t << 2) + s;
      int keyv = A[v] * NPTS + v;
      int pos = 0;
      for (int u = 0; u < NPTS; ++u) pos += ((A[u] * NPTS + u) < keyv) ? 1 : 0;
      B[v] = (pos >= NPTS - MAXSP) ? (pos - (NPTS - MAXSP)) : 0;
    }
    __syncthreads();
    for (int s = 0; s < 4; ++s){ int v = (t << 2) + s; LAB[v] = B[LAB[v]]; }
    __syncthreads();
  }
  int* og = out + (b << 12);
  for (int s = 0; s < 4; ++s){ int v = (t << 2) + s; og[v] = LAB[v]; }
}

// ---------------- launch ----------------------------------------------------
extern "C" void kernel_launch(void* const* d_in, const int* in_sizes, int n_in,
                              void* d_out, int out_size, void* d_ws, size_t ws_size,
                              hipStream_t stream){
  const float* coords = (const float*)d_in[0];
  int* out = (int*)d_out;
  int batches = in_sizes[0] / (NPTS * 3);   // 8

  char* ws = (char*)d_ws;
  unsigned long long* adj = (unsigned long long*)ws;                  // 16 MB
  size_t off = (size_t)batches * NPTS * NW * sizeof(unsigned long long);
  int* parent = (int*)(ws + off); off += (size_t)batches * NPTS * sizeof(int);
  int* core   = (int*)(ws + off); off += (size_t)batches * NPTS * sizeof(int);
  unsigned long long* corebits = (unsigned long long*)(ws + off);
  off += (size_t)batches * 64 * sizeof(unsigned long long);
  int* labels = (int*)(ws + off); off += (size_t)batches * NPTS * sizeof(int);
  float4* pts = (float4*)(ws + off); off += (size_t)batches * NPTS * sizeof(float4);

  int npts_all = batches * NPTS;
  // K0: pack float4(x,y,z,sq)
  k_prep<<<npts_all / 256, 256, 0, stream>>>(coords, pts);
  // K1: adjacency, 8 rows per wave
  k_adj<<<npts_all / (ROWS * 4), 256, 0, stream>>>(pts, adj, core);
  // K2: core bitset
  k_corebits<<<batches, 64, 0, stream>>>(core, corebits);
  // K3a: min-neighbor hook (atomic-free)
  k_hook<<<npts_all / 4, 256, 0, stream>>>(adj, corebits, core, parent);
  // K3b: union inter-tree edges
  k_union2<<<npts_all / 4, 256, 0, stream>>>(adj, corebits, core, parent);
  // K4: label extraction
  k_labels<<<npts_all / 4, 256, 0, stream>>>(adj, corebits, core, parent, labels);
  // K5: per-batch finalize
  k_final<<<batches, 1024, 0, stream>>>(labels, out);
}